// Round 9
// baseline (129.003 us; speedup 1.0000x reference)
//
#include <hip/hip_runtime.h>
#include <hip/hip_fp16.h>

// gap_2370821948148 — circle-loss scalar reduction. B=4096, K=64, N=65.
// r26: BURST-FIRST REORDER. Same structure as r25 (127.9us best) but each
// wave ISSUES its value-load burst BEFORE the preamble (mask detect, T,
// points, ballots), so preamble latency (~500cy) hides under the burst's
// memory latency instead of serializing ahead of it. Preamble is
// DUPLICATED into each w-branch: hoisting it out would make ch[64r] and
// vcol[64r] co-live through shared code -> 128+ regs -> spill at cap 102.
//
// SESSION LEDGER (why this shape):
//   - f32 inputs / bf16 scalar output (r5 inf proved f32; r2/r6 exact-0.0
//     proved the u16 bf16 readback).
//   - ~97us harness-fixed: 276MB ws 0xAA re-poison (~42us fill) + input
//     restores + graph gaps. Controllable = kernels (~31us).
//   - r18 WIN (131.9): f32 tile + VGPR cap up + fdot2.
//   - r19 REGRESS (139.2): coop staging + barrier (17KB vmcnt drain).
//   - r20 WIN (130.4): zero-LDS, lane-local row gathers + readlane.
//   - r21 REGRESS (132.4): VGPR_Count=44 proof of compiler LOAD-SINKING.
//   - r22 WIN (129.1): "+v" pin + asm memory fence -> one latency period.
//   - r23 REGRESS (134.8): tiny barriers cost ~5us. NO BARRIERS EVER.
//   - r24 WIN (128.4): 2048 blocks x 4 indep waves (CP theory mostly dead).
//   - r25 WIN (127.9, best): minwaves 3->5 (VGPR cap 102), occupancy up.
//   - SPILL TRAP (r11/r12/r14/r15): fired at minwaves>=7 WITH barrier;
//     also fires if ch+vcol co-live (see above). r26: branches disjoint,
//     no barrier, minwaves=5.
//   - DO-NOT-USE: single-kernel last-block finalize (r3/r4 silent out==0).
//
// Structure: 2 batches/block, 256 thr = 4 independent waves.
//   wv&1==0: loss1. Lane l = row l: issue 16 float4 + slack FIRST, then
//            preamble, pin+fence, compute (anchors via v_readlane).
//   wv&1==1: loss2. Lane l = col l: issue 64 dwords + slack FIRST, then
//            preamble, pin+fence, compute (points via v_readlane).
//   hc[32] packed-f16 hinge in regs; butterfly; partials to ws.
//   Separate unconditional finalize writes 4-byte dual-encoded bf16.

#define R2_POS 0.36f     // 0.6^2
#define R2_NEG 1.44f     // (2*0.6)^2
#define GAMMA_C 0.5f
#define NBATCH 4096
#define NPART (NBATCH * 2)
#define HCNEG -1024.0f   // hinge filler: ps+gamma+HCNEG << 0 in f16 range

typedef _Float16 hf2 __attribute__((ext_vector_type(2)));
typedef float f4v __attribute__((ext_vector_type(4)));

__device__ __forceinline__ int maskbit(const void* p, int i, int mode) {
    if (mode == 0) return ((const unsigned*)p)[i] != 0u;          // 4B elems
    if (mode == 1) return ((const unsigned short*)p)[i] != 0;     // 2B elems
    return ((const unsigned char*)p)[i] != 0;                     // u8/bool
}

__device__ __forceinline__ float sload(float v) {   // pin uniform to SGPR
    return __uint_as_float(__builtin_amdgcn_readfirstlane(__float_as_uint(v)));
}

__device__ __forceinline__ float rlane(float v, int i) {  // wave broadcast
    return __uint_as_float(__builtin_amdgcn_readlane(__float_as_uint(v), i));
}

__global__ __launch_bounds__(256, 5)
void fused_kernel(const float* __restrict__ posp,
                  const float* __restrict__ ancp,
                  const void* __restrict__ pmp,
                  const void* __restrict__ amp,
                  const float* __restrict__ msp,
                  const float* __restrict__ xfp,
                  float* __restrict__ partials) {
    const int tid = threadIdx.x;
    const int wv = tid >> 6;             // wave 0..3 (independent)
    const int l = tid & 63;              // lane
    const int b = blockIdx.x * 2 + (wv >> 1);   // batch for this wave
    const int w = wv & 1;                // 0 = rows (loss1), 1 = cols (loss2)

    float psum = 0.f; int pcnt = 0; float slack;
    float result;
    hf2 hc[32];                          // packed hinge candidates (32 VGPR)

    if (w == 0) {
        // ===== loss1: lane l = row l =====================================
        // ---- (1) ISSUE value burst first: 16 float4 + slack ----
        const float* rowp = msp + (size_t)b * 4225 + l * 65;
        f4v ch[16];
#pragma unroll
        for (int c = 0; c < 16; ++c)
            __builtin_memcpy(&ch[c], rowp + 4 * c, 16);   // global_load_dwordx4
        slack = rowp[64];

        // ---- (2) preamble hides under the burst ----
        unsigned mw0 = ((const unsigned*)pmp)[l];
        bool okw = (mw0 == 0u) || (mw0 == 1u) || (mw0 == 0x3F800000u);
        unsigned hh0 = mw0 & 0xFFFFu, hh1 = mw0 >> 16;
        bool okh = (hh0 == 0u || hh0 == 0x3F80u) && (hh1 == 0u || hh1 == 0x3F80u);
        int mmode = (__ballot(okw) == ~0ULL) ? 0 : ((__ballot(okh) == ~0ULL) ? 1 : 2);

        float T[12];
#pragma unroll
        for (int e = 0; e < 3; ++e)
#pragma unroll
            for (int d = 0; d < 4; ++d) T[e * 4 + d] = sload(xfp[e * 4 + d]);

        const int pb = (b * 64 + l) * 3;
        const float px = posp[pb], py = posp[pb + 1], pz = posp[pb + 2];
        const float r0 = ancp[pb], r1 = ancp[pb + 1], r2 = ancp[pb + 2];
        const float ax = T[0] * r0 + T[1] * r1 + T[2]  * r2 + T[3];
        const float ay = T[4] * r0 + T[5] * r1 + T[6]  * r2 + T[7];
        const float az = T[8] * r0 + T[9] * r1 + T[10] * r2 + T[11];

        const int mi = b * 64 + l;
        const unsigned long long pmM = __ballot(maskbit(pmp, mi, mmode) != 0);
        const unsigned long long amM = __ballot(maskbit(amp, mi, mmode) != 0);

        // ---- (3) pin + fence: value loads complete here ----
#pragma unroll
        for (int c = 0; c < 16; ++c) asm volatile("" : "+v"(ch[c]));
        asm volatile("" : "+v"(slack));
        asm volatile("" ::: "memory");

        // ---- (4) compute ----
        const bool pmL = (pmM >> l) & 1ULL;
#pragma unroll
        for (int jj = 0; jj < 32; ++jj) {
            float h0, h1;
#pragma unroll
            for (int s = 0; s < 2; ++s) {
                const int j = 2 * jj + s;
                float v = ch[j >> 2][j & 3];           // register
                float bx = rlane(ax, j);               // anchor j broadcast
                float by = rlane(ay, j);
                float bz = rlane(az, j);
                float dx = px - bx, dy = py - by, dz = pz - bz;
                float d2 = dx * dx + dy * dy + dz * dz;
                bool pos = pmL && ((amM >> j) & 1ULL) && (d2 < R2_POS);
                psum -= pos ? v : 0.f;
                pcnt += pos ? 1 : 0;
                float hcv = (d2 > R2_NEG) ? v : HCNEG; // gt_neg UNMASKED
                if (s == 0) h0 = hcv; else h1 = hcv;
            }
            hf2 h; h[0] = (_Float16)h0; h[1] = (_Float16)h1;
            hc[jj] = h;
        }
    } else {
        // ===== loss2: lane l = col l =====================================
        // ---- (1) ISSUE value burst first: 64 coalesced dwords + slack ----
        const float* mcol = msp + (size_t)b * 4225 + l;
        float vcol[64];
#pragma unroll
        for (int r = 0; r < 64; ++r) vcol[r] = mcol[r * 65];
        slack = mcol[64 * 65];

        // ---- (2) preamble hides under the burst ----
        unsigned mw0 = ((const unsigned*)pmp)[l];
        bool okw = (mw0 == 0u) || (mw0 == 1u) || (mw0 == 0x3F800000u);
        unsigned hh0 = mw0 & 0xFFFFu, hh1 = mw0 >> 16;
        bool okh = (hh0 == 0u || hh0 == 0x3F80u) && (hh1 == 0u || hh1 == 0x3F80u);
        int mmode = (__ballot(okw) == ~0ULL) ? 0 : ((__ballot(okh) == ~0ULL) ? 1 : 2);

        float T[12];
#pragma unroll
        for (int e = 0; e < 3; ++e)
#pragma unroll
            for (int d = 0; d < 4; ++d) T[e * 4 + d] = sload(xfp[e * 4 + d]);

        const int pb = (b * 64 + l) * 3;
        const float px = posp[pb], py = posp[pb + 1], pz = posp[pb + 2];
        const float r0 = ancp[pb], r1 = ancp[pb + 1], r2 = ancp[pb + 2];
        const float ax = T[0] * r0 + T[1] * r1 + T[2]  * r2 + T[3];
        const float ay = T[4] * r0 + T[5] * r1 + T[6]  * r2 + T[7];
        const float az = T[8] * r0 + T[9] * r1 + T[10] * r2 + T[11];

        const int mi = b * 64 + l;
        const unsigned long long pmM = __ballot(maskbit(pmp, mi, mmode) != 0);
        const unsigned long long amM = __ballot(maskbit(amp, mi, mmode) != 0);

        // ---- (3) pin + fence ----
#pragma unroll
        for (int r = 0; r < 64; ++r) asm volatile("" : "+v"(vcol[r]));
        asm volatile("" : "+v"(slack));
        asm volatile("" ::: "memory");

        // ---- (4) compute ----
        const bool amL = (amM >> l) & 1ULL;
#pragma unroll
        for (int jj = 0; jj < 32; ++jj) {
            float h0, h1;
#pragma unroll
            for (int s = 0; s < 2; ++s) {
                const int r = 2 * jj + s;
                float v = vcol[r];                     // register
                float qx = rlane(px, r);               // point r broadcast
                float qy = rlane(py, r);
                float qz = rlane(pz, r);
                float dx = qx - ax, dy = qy - ay, dz = qz - az;
                float d2 = dx * dx + dy * dy + dz * dz;
                bool pos = ((pmM >> r) & 1ULL) && amL && (d2 < R2_POS);
                psum -= pos ? v : 0.f;
                pcnt += pos ? 1 : 0;
                float hcv = (d2 > R2_NEG) ? v : HCNEG;
                if (s == 0) h0 = hcv; else h1 = hcv;
            }
            hf2 h; h[0] = (_Float16)h0; h[1] = (_Float16)h1;
            hc[jj] = h;
        }
    }

    const float ps = pcnt ? psum / (float)pcnt : -slack;

    // ---- packed branch-free hinge: max(hc + (ps+gamma), 0), f32 accum ----
    const _Float16 ch16 = (_Float16)(ps + GAMMA_C);
    const hf2 C2 = {ch16, ch16};
    const hf2 Z = {(_Float16)0.f, (_Float16)0.f};
    float hv = 0.f;
#if __has_builtin(__builtin_amdgcn_fdot2)
    const hf2 ONE2 = {(_Float16)1.f, (_Float16)1.f};
#pragma unroll
    for (int k = 0; k < 32; ++k) {
        hf2 x = hc[k] + C2;                  // v_pk_add_f16
        x = __builtin_elementwise_max(x, Z); // v_pk_max_f16
        hv = __builtin_amdgcn_fdot2(x, ONE2, hv, false); // v_dot2_f32_f16
    }
#else
#pragma unroll
    for (int k = 0; k < 32; ++k) {
        hf2 x = hc[k] + C2;                  // v_pk_add_f16
        x = __builtin_elementwise_max(x, Z); // v_pk_max_f16
        hv += (float)x[0] + (float)x[1];
    }
#endif
    if (pcnt) hv += fmaxf(ps + slack + GAMMA_C, 0.f);
    result = __logf(hv + 1.f);

    // ---- one butterfly per wave, lane0 stores partial ----
#pragma unroll
    for (int off = 1; off < 64; off <<= 1)
        result += __shfl_xor(result, off, 64);
    if (l == 0) partials[b * 2 + w] = result;          // plain store, no init
}

// Separate unconditional finalize (proven). 4-byte dual-encoded write:
// low u16 = exact bf16 bits; as f32 also decodes to ~value(h).
__global__ void finalize_kernel(const float* __restrict__ partials,
                                unsigned* __restrict__ out) {
    __shared__ float red[4];
    const int tid = threadIdx.x;
    float s = 0.f;
    for (int i = tid; i < NPART; i += 256) s += partials[i];
#pragma unroll
    for (int off = 1; off < 64; off <<= 1) s += __shfl_xor(s, off, 64);
    if ((tid & 63) == 0) red[tid >> 6] = s;
    __syncthreads();
    if (tid == 0) {
        float tot = red[0] + red[1] + red[2] + red[3];
        float loss = tot * (1.0f / (2.0f * NBATCH * 64.0f));
        unsigned bits = __float_as_uint(loss);
        unsigned h = (bits + 0x7FFFu + ((bits >> 16) & 1u)) >> 16;  // rne bf16
        out[0] = (h << 16) | h;
    }
}

extern "C" void kernel_launch(void* const* d_in, const int* in_sizes, int n_in,
                              void* d_out, int out_size, void* d_ws, size_t ws_size,
                              hipStream_t stream) {
    (void)in_sizes; (void)n_in; (void)out_size; (void)ws_size;
    const float* posp = (const float*)d_in[0];
    const float* ancp = (const float*)d_in[1];
    const void* pmp = d_in[2];
    const void* amp = d_in[3];
    const float* msp = (const float*)d_in[4];
    const float* xfp = (const float*)d_in[5];

    // ws[0..NPART): per-wave partials, fully overwritten every call.
    // 2048 blocks x 4 independent waves.
    fused_kernel<<<NBATCH / 2, 256, 0, stream>>>(posp, ancp, pmp, amp, msp,
                                                 xfp, (float*)d_ws);
    finalize_kernel<<<1, 256, 0, stream>>>((const float*)d_ws,
                                           (unsigned*)d_out);
}

// Round 10
// 120.690 us; speedup vs baseline: 1.0689x; 1.0689x over previous
//
#include <hip/hip_runtime.h>
#include <hip/hip_fp16.h>

// gap_2370821948148 — circle-loss scalar reduction. B=4096, K=64, N=65.
// r27: LOCK BEST + finalize trim. Fused kernel = r25 byte-identical
// (127.9us session best). Finalize: float4-vectorized reads, 512 thr,
// 8-wave LDS reduce (off the fused value path — barrier allowed here).
//
// SESSION LEDGER (why this shape):
//   - f32 inputs / bf16 scalar output (r5 inf proved f32; r2/r6 exact-0.0
//     proved the u16 bf16 readback).
//   - ~97us harness-fixed: 276MB ws 0xAA re-poison (~42us fill) + input
//     restores + graph gaps. Controllable = kernels (~31us).
//   - r18 WIN (131.9): f32 tile + VGPR cap up + fdot2.
//   - r19 REGRESS (139.2): coop staging + barrier (17KB vmcnt drain).
//   - r20 WIN (130.4): zero-LDS, lane-local row gathers + readlane.
//   - r21 REGRESS (132.4): VGPR_Count=44 proof of compiler LOAD-SINKING.
//   - r22 WIN (129.1): "+v" pin + asm memory fence -> one latency period.
//   - r23 REGRESS (134.8): tiny barriers cost ~5us on fused path. NEVER.
//   - r24 WIN (128.4): 2048 blocks x 4 indep waves (CP theory mostly dead).
//   - r25 WIN (127.9, BEST): minwaves 3->5 (VGPR cap 102).
//   - r26 REGRESS (129.0): burst-before-preamble — mask/ballot loads
//     queued behind 65 value loads; issue order r25 restored.
//   - SPILL TRAP (r11/r12/r14/r15): fired at minwaves>=7 WITH barrier;
//     or ch+vcol co-live. r27 fused: branches disjoint, no barrier, mw=5.
//   - DO-NOT-USE: single-kernel last-block finalize (r3/r4 silent out==0).
//
// Structure: 2 batches/block, 256 thr = 4 independent waves.
//   wv&1==0: loss1. Lane l = row l: 16 float4 + slack, pinned+fenced;
//            anchors j via v_readlane. hc[32] packed-f16 hinge.
//   wv&1==1: loss2. Lane l = col l: 64 coalesced dwords + slack, pinned+
//            fenced; points r via v_readlane. Same hinge.
//   Partials to ws (plain stores, poison-proof), separate unconditional
//   finalize writes 4-byte dual-encoded bf16 (exact under u16 readback).

#define R2_POS 0.36f     // 0.6^2
#define R2_NEG 1.44f     // (2*0.6)^2
#define GAMMA_C 0.5f
#define NBATCH 4096
#define NPART (NBATCH * 2)
#define HCNEG -1024.0f   // hinge filler: ps+gamma+HCNEG << 0 in f16 range

typedef _Float16 hf2 __attribute__((ext_vector_type(2)));
typedef float f4v __attribute__((ext_vector_type(4)));

__device__ __forceinline__ int maskbit(const void* p, int i, int mode) {
    if (mode == 0) return ((const unsigned*)p)[i] != 0u;          // 4B elems
    if (mode == 1) return ((const unsigned short*)p)[i] != 0;     // 2B elems
    return ((const unsigned char*)p)[i] != 0;                     // u8/bool
}

__device__ __forceinline__ float sload(float v) {   // pin uniform to SGPR
    return __uint_as_float(__builtin_amdgcn_readfirstlane(__float_as_uint(v)));
}

__device__ __forceinline__ float rlane(float v, int i) {  // wave broadcast
    return __uint_as_float(__builtin_amdgcn_readlane(__float_as_uint(v), i));
}

__global__ __launch_bounds__(256, 5)
void fused_kernel(const float* __restrict__ posp,
                  const float* __restrict__ ancp,
                  const void* __restrict__ pmp,
                  const void* __restrict__ amp,
                  const float* __restrict__ msp,
                  const float* __restrict__ xfp,
                  float* __restrict__ partials) {
    const int tid = threadIdx.x;
    const int wv = tid >> 6;             // wave 0..3 (independent)
    const int l = tid & 63;              // lane
    const int b = blockIdx.x * 2 + (wv >> 1);   // batch for this wave
    const int w = wv & 1;                // 0 = rows (loss1), 1 = cols (loss2)

    // ---- mask element-width detection (uniform, cached) ----
    unsigned mw0 = ((const unsigned*)pmp)[l];
    bool okw = (mw0 == 0u) || (mw0 == 1u) || (mw0 == 0x3F800000u);
    unsigned hh0 = mw0 & 0xFFFFu, hh1 = mw0 >> 16;
    bool okh = (hh0 == 0u || hh0 == 0x3F80u) && (hh1 == 0u || hh1 == 0x3F80u);
    int mmode = (__ballot(okw) == ~0ULL) ? 0 : ((__ballot(okh) == ~0ULL) ? 1 : 2);

    // ---- transform, pinned to SGPRs ----
    float T[12];
#pragma unroll
    for (int e = 0; e < 3; ++e)
#pragma unroll
        for (int d = 0; d < 4; ++d) T[e * 4 + d] = sload(xfp[e * 4 + d]);

    // ---- own points: lane l = point l of batch b ----
    const int pb = (b * 64 + l) * 3;
    const float px = posp[pb], py = posp[pb + 1], pz = posp[pb + 2];
    const float r0 = ancp[pb], r1 = ancp[pb + 1], r2 = ancp[pb + 2];
    const float ax = T[0] * r0 + T[1] * r1 + T[2]  * r2 + T[3];
    const float ay = T[4] * r0 + T[5] * r1 + T[6]  * r2 + T[7];
    const float az = T[8] * r0 + T[9] * r1 + T[10] * r2 + T[11];

    // ---- masks -> per-wave ballots (SGPR pairs) ----
    const int mi = b * 64 + l;
    const unsigned long long pmM = __ballot(maskbit(pmp, mi, mmode) != 0);
    const unsigned long long amM = __ballot(maskbit(amp, mi, mmode) != 0);

    float psum = 0.f; int pcnt = 0; float slack;
    hf2 hc[32];                          // packed hinge candidates (32 VGPR)

    if (w == 0) {
        // ===== loss1: lane l = row l; 65 contiguous floats, lane-local ====
        const float* rowp = msp + (size_t)b * 4225 + l * 65;
        f4v ch[16];
#pragma unroll
        for (int c = 0; c < 16; ++c)
            __builtin_memcpy(&ch[c], rowp + 4 * c, 16);   // global_load_dwordx4
        slack = rowp[64];
        // ---- pin + fence: loads may NOT sink below this point ----
#pragma unroll
        for (int c = 0; c < 16; ++c) asm volatile("" : "+v"(ch[c]));
        asm volatile("" : "+v"(slack));
        asm volatile("" ::: "memory");

        const bool pmL = (pmM >> l) & 1ULL;
#pragma unroll
        for (int jj = 0; jj < 32; ++jj) {
            float h0, h1;
#pragma unroll
            for (int s = 0; s < 2; ++s) {
                const int j = 2 * jj + s;
                float v = ch[j >> 2][j & 3];           // register
                float bx = rlane(ax, j);               // anchor j broadcast
                float by = rlane(ay, j);
                float bz = rlane(az, j);
                float dx = px - bx, dy = py - by, dz = pz - bz;
                float d2 = dx * dx + dy * dy + dz * dz;
                bool pos = pmL && ((amM >> j) & 1ULL) && (d2 < R2_POS);
                psum -= pos ? v : 0.f;
                pcnt += pos ? 1 : 0;
                float hcv = (d2 > R2_NEG) ? v : HCNEG; // gt_neg UNMASKED
                if (s == 0) h0 = hcv; else h1 = hcv;
            }
            hf2 h; h[0] = (_Float16)h0; h[1] = (_Float16)h1;
            hc[jj] = h;
        }
    } else {
        // ===== loss2: lane l = col l; 64 coalesced dwords + slack, pinned =
        const float* mcol = msp + (size_t)b * 4225 + l;
        float vcol[64];
#pragma unroll
        for (int r = 0; r < 64; ++r) vcol[r] = mcol[r * 65];
        slack = mcol[64 * 65];
        // ---- pin + fence: loads may NOT sink below this point ----
#pragma unroll
        for (int r = 0; r < 64; ++r) asm volatile("" : "+v"(vcol[r]));
        asm volatile("" : "+v"(slack));
        asm volatile("" ::: "memory");

        const bool amL = (amM >> l) & 1ULL;
#pragma unroll
        for (int jj = 0; jj < 32; ++jj) {
            float h0, h1;
#pragma unroll
            for (int s = 0; s < 2; ++s) {
                const int r = 2 * jj + s;
                float v = vcol[r];                     // register
                float qx = rlane(px, r);               // point r broadcast
                float qy = rlane(py, r);
                float qz = rlane(pz, r);
                float dx = qx - ax, dy = qy - ay, dz = qz - az;
                float d2 = dx * dx + dy * dy + dz * dz;
                bool pos = ((pmM >> r) & 1ULL) && amL && (d2 < R2_POS);
                psum -= pos ? v : 0.f;
                pcnt += pos ? 1 : 0;
                float hcv = (d2 > R2_NEG) ? v : HCNEG;
                if (s == 0) h0 = hcv; else h1 = hcv;
            }
            hf2 h; h[0] = (_Float16)h0; h[1] = (_Float16)h1;
            hc[jj] = h;
        }
    }

    const float ps = pcnt ? psum / (float)pcnt : -slack;

    // ---- packed branch-free hinge: max(hc + (ps+gamma), 0), f32 accum ----
    const _Float16 ch16 = (_Float16)(ps + GAMMA_C);
    const hf2 C2 = {ch16, ch16};
    const hf2 Z = {(_Float16)0.f, (_Float16)0.f};
    float hv = 0.f;
#if __has_builtin(__builtin_amdgcn_fdot2)
    const hf2 ONE2 = {(_Float16)1.f, (_Float16)1.f};
#pragma unroll
    for (int k = 0; k < 32; ++k) {
        hf2 x = hc[k] + C2;                  // v_pk_add_f16
        x = __builtin_elementwise_max(x, Z); // v_pk_max_f16
        hv = __builtin_amdgcn_fdot2(x, ONE2, hv, false); // v_dot2_f32_f16
    }
#else
#pragma unroll
    for (int k = 0; k < 32; ++k) {
        hf2 x = hc[k] + C2;                  // v_pk_add_f16
        x = __builtin_elementwise_max(x, Z); // v_pk_max_f16
        hv += (float)x[0] + (float)x[1];
    }
#endif
    if (pcnt) hv += fmaxf(ps + slack + GAMMA_C, 0.f);
    float result = __logf(hv + 1.f);

    // ---- one butterfly per wave, lane0 stores partial ----
#pragma unroll
    for (int off = 1; off < 64; off <<= 1)
        result += __shfl_xor(result, off, 64);
    if (l == 0) partials[b * 2 + w] = result;          // plain store, no init
}

// Separate unconditional finalize (proven shape). float4 reads, 512 thr,
// 8-wave LDS reduce. Barrier OK here (off the fused value path).
// 4-byte dual-encoded write: low u16 = exact bf16 bits.
__global__ __launch_bounds__(512)
void finalize_kernel(const float* __restrict__ partials,
                     unsigned* __restrict__ out) {
    __shared__ float red[8];
    const int tid = threadIdx.x;
    float s = 0.f;
    // NPART floats = NPART/4 float4s; 512 threads -> 4 float4 each.
    const f4v* p4 = (const f4v*)partials;
#pragma unroll
    for (int k = 0; k < NPART / 4 / 512; ++k) {
        f4v v = p4[tid + 512 * k];
        s += v[0] + v[1] + v[2] + v[3];
    }
#pragma unroll
    for (int off = 1; off < 64; off <<= 1) s += __shfl_xor(s, off, 64);
    if ((tid & 63) == 0) red[tid >> 6] = s;
    __syncthreads();
    if (tid == 0) {
        float tot = 0.f;
#pragma unroll
        for (int i = 0; i < 8; ++i) tot += red[i];
        float loss = tot * (1.0f / (2.0f * NBATCH * 64.0f));
        unsigned bits = __float_as_uint(loss);
        unsigned h = (bits + 0x7FFFu + ((bits >> 16) & 1u)) >> 16;  // rne bf16
        out[0] = (h << 16) | h;
    }
}

extern "C" void kernel_launch(void* const* d_in, const int* in_sizes, int n_in,
                              void* d_out, int out_size, void* d_ws, size_t ws_size,
                              hipStream_t stream) {
    (void)in_sizes; (void)n_in; (void)out_size; (void)ws_size;
    const float* posp = (const float*)d_in[0];
    const float* ancp = (const float*)d_in[1];
    const void* pmp = d_in[2];
    const void* amp = d_in[3];
    const float* msp = (const float*)d_in[4];
    const float* xfp = (const float*)d_in[5];

    // ws[0..NPART): per-wave partials, fully overwritten every call.
    // 2048 blocks x 4 independent waves.
    fused_kernel<<<NBATCH / 2, 256, 0, stream>>>(posp, ancp, pmp, amp, msp,
                                                 xfp, (float*)d_ws);
    finalize_kernel<<<1, 512, 0, stream>>>((const float*)d_ws,
                                           (unsigned*)d_out);
}